// Round 7
// baseline (276.773 us; speedup 1.0000x reference)
//
#include <hip/hip_runtime.h>

typedef unsigned short u16;
typedef __attribute__((ext_vector_type(8))) __bf16 bf16x8;
typedef __attribute__((ext_vector_type(4))) float f32x4;
typedef __attribute__((ext_vector_type(16))) float f32x16;

__device__ __forceinline__ u16 f2bf(float f) {
    union { float f; unsigned u; } v; v.f = f;
    unsigned u = v.u;
    u += 0x7FFFu + ((u >> 16) & 1u);
    return (u16)(u >> 16);
}

// pack two f32 -> u32 of 2x bf16 (RNE); compiler emits v_cvt_pk_bf16_f32 (m240)
__device__ __forceinline__ unsigned pk2(float lo, float hi) {
    union { __bf16 h[2]; unsigned u; } x;
    x.h[0] = (__bf16)lo; x.h[1] = (__bf16)hi;
    return x.u;
}
// exchange upper 32 lanes of a with lower 32 lanes of b (compiler-managed hazards)
__device__ __forceinline__ void pswap(unsigned &a, unsigned &b) {
    auto r = __builtin_amdgcn_permlane32_swap(a, b, false, false);
    a = r[0]; b = r[1];
}

// async global->LDS copy, 16B per lane (m97 pattern)
typedef const __attribute__((address_space(1))) void GV;
typedef __attribute__((address_space(3))) void LV;
__device__ __forceinline__ void gl2lds16(const void* g, void* l) {
    __builtin_amdgcn_global_load_lds((GV*)g, (LV*)l, 16, 0, 0);
}

// ---------------- fused cast fp32 -> bf16 (x + 4 weights in ONE launch) ----------------
__global__ __launch_bounds__(256) void cast_all(
    const float* __restrict__ x,  const float* __restrict__ Wq,
    const float* __restrict__ Wk, const float* __restrict__ Wv,
    const float* __restrict__ Wp,
    u16* __restrict__ xb, u16* __restrict__ wb, u16* __restrict__ wpb)
{
    int bid = blockIdx.x;
    const float4* s; ushort4* d; int idx;
    if (bid < 6144) {                    // x: 1572864 float4 = 6144 blocks
        s = (const float4*)x; d = (ushort4*)xb; idx = bid * 256 + threadIdx.x;
    } else {                             // weights: 147456 float4 = 576 blocks each
        int t = bid - 6144;
        int w = t / 576;
        idx = (t - w * 576) * 256 + threadIdx.x;
        s = (const float4*)(w == 0 ? Wq : w == 1 ? Wk : w == 2 ? Wv : Wp);
        d = (ushort4*)(w == 3 ? wpb : wb + w * 589824);
    }
    float4 f = s[idx];
    ushort4 o;
    o.x = f2bf(f.x); o.y = f2bf(f.y); o.z = f2bf(f.z); o.w = f2bf(f.w);
    d[idx] = o;
}

// ---------------- GEMM v9 staging: BK=32 tiles, LDS line-XOR swizzle ----------------
// Tile rows are 32 bf16 = 64 B; LDS stores 2-row LINES of 128 B / 8 chunks.
// Lane-linear LDS dest (global_load_lds constraint): phys chunk `pos` of line
// holds LOGICAL chunk pos ^ (line&7). Frag column read -> 2-way bank alias =
// free (verified SQ_LDS_BANK_CONFLICT=0, rounds 1/6).
__device__ __forceinline__ void stage_c(const u16* src, int k0, u16* lds, int i) {
    int line = i >> 3, pos = i & 7;
    int p = pos ^ (line & 7);                 // logical chunk in this phys slot
    int r = line * 2 + (p >> 2), c = p & 3;
    gl2lds16(src + (size_t)r * 768 + k0 + c * 8, lds + i * 8);
}
__device__ __forceinline__ const bf16x8* fragK(const u16* lds, int row, int quad) {
    int line = row >> 1;
    int pos = (((row & 1) << 2) | quad) ^ (line & 7);
    return reinterpret_cast<const bf16x8*>(lds + line * 64 + pos * 8);
}

// ---------------- QKV projection GEMM (v9: BM=128/BN=192, 768 blocks = 3.0/CU) ----------------
// Load-balance fix: 64x12 = 768 blocks / 256 CU = exactly 3 blocks per CU
// (r0-r6 all had 2.25/CU -> 1.33x makespan imbalance). 40 KB LDS -> 3 resident,
// 24 waves/CU. Stage-ahead double buffer, 1 barrier/iter (attn's proven pattern;
// counted-vmcnt dropped -- proven null at 2-phase, m230).
__global__ __launch_bounds__(512, 6) void gemm_qkv(
    const u16* __restrict__ A, const u16* __restrict__ Bm,
    u16* __restrict__ qo, u16* __restrict__ ko, u16* __restrict__ vto)
{
    __shared__ u16 As[2][4096];          // 2 x  8 KB (128 rows x 32)
    __shared__ u16 Bs[2][6144];          // 2 x 12 KB (192 rows x 32)
    const int tid = threadIdx.x;
    const int wave = tid >> 6, lane = tid & 63;
    const int quad = lane >> 4, l16 = lane & 15;
    const int wm = wave >> 2, wn = wave & 3;      // 2M x 4N waves, per-wave 64x48
    // XCD-chunked swizzle (T1): 768 blocks = 8 XCDs x 96 (bijective, 768%8==0)
    const int id = blockIdx.x + 12 * blockIdx.y;
    const int nid = (id & 7) * 96 + (id >> 3);
    const int bx = nid % 12, by = nid / 12;
    const int rowBase = by * 128;
    const int colBase = bx * 192;

    const u16* aSrc = A + (size_t)rowBase * 768;
    const u16* bSrc = Bm + (size_t)colBase * 768;
    f32x4 acc[4][3] = {};

    // stage one BK=32 tile: A 512 chunks (1/thread), B 768 chunks (1.5/thread,
    // wave-uniform split at tid<256 = waves 0-3)
    auto stage = [&](int buf, int k0) {
        stage_c(aSrc, k0, As[buf], tid);
        stage_c(bSrc, k0, Bs[buf], tid);
        if (tid < 256) stage_c(bSrc, k0, Bs[buf], 512 + tid);
    };

    stage(0, 0);
    __syncthreads();                     // tile 0 staged (vmcnt drained at barrier)

    int buf = 0;
    for (int t = 0; t < 24; t++) {
        if (t + 1 < 24) stage(buf ^ 1, (t + 1) * 32);   // prefetch next tile
        bf16x8 a[4], b[3];
        #pragma unroll
        for (int mi = 0; mi < 4; mi++) a[mi] = *fragK(As[buf], wm * 64 + mi * 16 + l16, quad);
        #pragma unroll
        for (int ni = 0; ni < 3; ni++) b[ni] = *fragK(Bs[buf], wn * 48 + ni * 16 + l16, quad);
        __builtin_amdgcn_s_setprio(1);
        #pragma unroll
        for (int mi = 0; mi < 4; mi++)
            #pragma unroll
            for (int ni = 0; ni < 3; ni++)
                acc[mi][ni] = __builtin_amdgcn_mfma_f32_16x16x32_bf16(a[mi], b[ni], acc[mi][ni], 0, 0, 0);
        __builtin_amdgcn_s_setprio(0);
        __syncthreads();                 // reads of buf done; next tile's stage drained
        buf ^= 1;
    }

    #pragma unroll
    for (int mi = 0; mi < 4; mi++) {
        #pragma unroll
        for (int ni = 0; ni < 3; ni++) {
            int gj = colBase + wn * 48 + ni * 16 + l16;   // 0..2303
            int which = gj / 768;                         // 0=q,1=k,2=v (uniform per frag)
            int r = gj - which * 768;
            int h = r >> 6, d = r & 63;
            int gi0 = rowBase + wm * 64 + mi * 16 + quad * 4;
            int b_ = gi0 >> 10;                           // constant across 4 rows
            int n0 = gi0 & 1023;
            if (which == 2) {
                ushort4 pk;
                pk.x = f2bf(acc[mi][ni][0]);
                pk.y = f2bf(acc[mi][ni][1]);
                pk.z = f2bf(acc[mi][ni][2]);
                pk.w = f2bf(acc[mi][ni][3]);
                *reinterpret_cast<ushort4*>(vto + ((size_t)(b_ * 12 + h) * 64 + d) * 1024 + n0) = pk;
            } else {
                float s = (which == 0) ? 0.125f : 1.0f;
                u16* dst = (which == 0 ? qo : ko) + ((size_t)(b_ * 12 + h) * 1024 + n0) * 64 + d;
                #pragma unroll
                for (int rr = 0; rr < 4; rr++)
                    dst[(size_t)rr * 64] = f2bf(acc[mi][ni][rr] * s);
            }
        }
    }
}

// ---------------- fused flash attention (v9.1, unchanged) ----------------
__global__ __launch_bounds__(256, 3) void attn_fwd(
    const u16* __restrict__ q, const u16* __restrict__ k,
    const u16* __restrict__ vt, u16* __restrict__ ao)
{
    __shared__ u16 Ks[2][4096];      // [key 0..63][d-chunk phys 0..7][8 bf16]
    __shared__ u16 Vs[2][4096];      // [d 0..63][key-chunk phys 0..7][8 bf16]
    const int bh = blockIdx.x, qt = blockIdx.y;   // bh fast => same head -> same XCD
    const int b = bh / 12, h = bh - b * 12;
    const int tid = threadIdx.x;
    const int wave = tid >> 6, lane = tid & 63;
    const int l31 = lane & 31, hi = lane >> 5;
    const int sw = l31 & 7;

    const u16* qb = q + (size_t)bh * 65536 + ((size_t)qt * 128 + wave * 32) * 64;
    const u16* kb = k + (size_t)bh * 65536;
    const u16* vb = vt + (size_t)bh * 65536;

    auto stage = [&](int buf, int j0) {
        #pragma unroll
        for (int r = 0; r < 2; r++) {
            int i = r * 256 + tid;               // 0..511, 16B each
            int row = i >> 3, cp = i & 7;
            int cl = cp ^ (row & 7);
            gl2lds16((const char*)kb + (size_t)(j0 + row) * 128 + cl * 16,
                     (char*)&Ks[buf][0] + i * 16);
        }
        #pragma unroll
        for (int r = 0; r < 2; r++) {
            int i = r * 256 + tid;
            int row = i >> 3, cp = i & 7;
            int cl = cp ^ (row & 7);
            gl2lds16((const char*)vb + (size_t)row * 2048 + (size_t)j0 * 2 + cl * 16,
                     (char*)&Vs[buf][0] + i * 16);
        }
    };

    stage(0, 0);

    bf16x8 qf[4];
    #pragma unroll
    for (int dk = 0; dk < 4; dk++)
        qf[dk] = *reinterpret_cast<const bf16x8*>(qb + l31 * 64 + dk * 16 + hi * 8);

    f32x16 o0 = {}, o1 = {};         // O[query 32][d 0-31 / 32-63]
    float lsum = 0.f;                // partial row-sum for query l31

    __syncthreads();

    int buf = 0;
    for (int j0 = 0; j0 < 1024; j0 += 64) {
        if (j0 + 64 < 1024) stage(buf ^ 1, j0 + 64);

        f32x16 s0 = {}, s1 = {};
        #pragma unroll
        for (int dk = 0; dk < 4; dk++) {
            int ch = ((2 * dk + hi) ^ sw) * 8;
            bf16x8 kf0 = *reinterpret_cast<const bf16x8*>(&Ks[buf][l31 * 64 + ch]);
            bf16x8 kf1 = *reinterpret_cast<const bf16x8*>(&Ks[buf][(32 + l31) * 64 + ch]);
            s0 = __builtin_amdgcn_mfma_f32_32x32x16_bf16(kf0, qf[dk], s0, 0, 0, 0);
            s1 = __builtin_amdgcn_mfma_f32_32x32x16_bf16(kf1, qf[dk], s1, 0, 0, 0);
        }

        bf16x8 pa[4];
        #pragma unroll
        for (int kbk = 0; kbk < 2; kbk++) {
            float p[16];
            #pragma unroll
            for (int r = 0; r < 16; r++) {
                p[r] = __expf(kbk ? s1[r] : s0[r]);
                lsum += p[r];
            }
            unsigned W00 = pk2(p[0],  p[1]),  W01 = pk2(p[2],  p[3]);
            unsigned W10 = pk2(p[4],  p[5]),  W11 = pk2(p[6],  p[7]);
            unsigned W20 = pk2(p[8],  p[9]),  W21 = pk2(p[10], p[11]);
            unsigned W30 = pk2(p[12], p[13]), W31 = pk2(p[14], p[15]);
            pswap(W00, W10); pswap(W01, W11);
            pswap(W20, W30); pswap(W21, W31);
            union { unsigned u[4]; bf16x8 v; } pk0, pk1;
            pk0.u[0] = W00; pk0.u[1] = W01; pk0.u[2] = W10; pk0.u[3] = W11;
            pk1.u[0] = W20; pk1.u[1] = W21; pk1.u[2] = W30; pk1.u[3] = W31;
            pa[kbk * 2 + 0] = pk0.v;
            pa[kbk * 2 + 1] = pk1.v;
        }

        #pragma unroll
        for (int ks = 0; ks < 4; ks++) {
            int ch = ((2 * ks + hi) ^ sw) * 8;
            bf16x8 vf0 = *reinterpret_cast<const bf16x8*>(&Vs[buf][l31 * 64 + ch]);
            bf16x8 vf1 = *reinterpret_cast<const bf16x8*>(&Vs[buf][(32 + l31) * 64 + ch]);
            o0 = __builtin_amdgcn_mfma_f32_32x32x16_bf16(pa[ks], vf0, o0, 0, 0, 0);
            o1 = __builtin_amdgcn_mfma_f32_32x32x16_bf16(pa[ks], vf1, o1, 0, 0, 0);
        }

        __syncthreads();
        buf ^= 1;
    }

    lsum += __shfl_xor(lsum, 32, 64);

    #pragma unroll
    for (int r = 0; r < 16; r++) {
        int qrow = (r & 3) + 8 * (r >> 2) + 4 * hi;
        float lv = __shfl(lsum, qrow, 32);
        float inv = 1.0f / lv;
        int n = qt * 128 + wave * 32 + qrow;
        size_t base = (size_t)(b * 1024 + n) * 768 + h * 64;
        ao[base + l31]      = f2bf(o0[r] * inv);
        ao[base + 32 + l31] = f2bf(o1[r] * inv);
    }
}

// ---------------- output projection GEMM (v9: BM=128/BN=96, 512 blocks = 2.0/CU) ----------------
__global__ __launch_bounds__(256, 3) void gemm_proj(
    const u16* __restrict__ A, const u16* __restrict__ Bm,
    const float* __restrict__ bias, float* __restrict__ out)
{
    __shared__ u16 As[2][4096];          // 2 x 8 KB (128 x 32)
    __shared__ u16 Bs[2][3072];          // 2 x 6 KB ( 96 x 32)
    const int tid = threadIdx.x;
    const int wave = tid >> 6, lane = tid & 63;
    const int quad = lane >> 4, l16 = lane & 15;
    const int wm = wave >> 1, wn = wave & 1;      // 2M x 2N waves, per-wave 64x48
    // XCD-chunked swizzle: 512 blocks = 8 XCDs x 64 (bijective)
    const int id = blockIdx.x + 8 * blockIdx.y;
    const int nid = (id & 7) * 64 + (id >> 3);
    const int bx = nid % 8, by = nid / 8;
    const int rowBase = by * 128;
    const int colBase = bx * 96;

    const u16* aSrc = A + (size_t)rowBase * 768;
    const u16* bSrc = Bm + (size_t)colBase * 768;
    f32x4 acc[4][3] = {};

    // A 512 chunks (2/thread), B 384 chunks (1.5/thread, split at tid<128 = waves 0-1)
    auto stage = [&](int buf, int k0) {
        stage_c(aSrc, k0, As[buf], tid);
        stage_c(aSrc, k0, As[buf], 256 + tid);
        stage_c(bSrc, k0, Bs[buf], tid);
        if (tid < 128) stage_c(bSrc, k0, Bs[buf], 256 + tid);
    };

    stage(0, 0);
    __syncthreads();

    int buf = 0;
    for (int t = 0; t < 24; t++) {
        if (t + 1 < 24) stage(buf ^ 1, (t + 1) * 32);
        bf16x8 a[4], b[3];
        #pragma unroll
        for (int mi = 0; mi < 4; mi++) a[mi] = *fragK(As[buf], wm * 64 + mi * 16 + l16, quad);
        #pragma unroll
        for (int ni = 0; ni < 3; ni++) b[ni] = *fragK(Bs[buf], wn * 48 + ni * 16 + l16, quad);
        __builtin_amdgcn_s_setprio(1);
        #pragma unroll
        for (int mi = 0; mi < 4; mi++)
            #pragma unroll
            for (int ni = 0; ni < 3; ni++)
                acc[mi][ni] = __builtin_amdgcn_mfma_f32_16x16x32_bf16(a[mi], b[ni], acc[mi][ni], 0, 0, 0);
        __builtin_amdgcn_s_setprio(0);
        __syncthreads();
        buf ^= 1;
    }

    #pragma unroll
    for (int mi = 0; mi < 4; mi++) {
        #pragma unroll
        for (int ni = 0; ni < 3; ni++) {
            int gj = colBase + wn * 48 + ni * 16 + l16;
            float bv = bias[gj];
            int gi0 = rowBase + wm * 64 + mi * 16 + quad * 4;
            #pragma unroll
            for (int rr2 = 0; rr2 < 4; rr2++)
                out[(size_t)(gi0 + rr2) * 768 + gj] = acc[mi][ni][rr2] + bv;
        }
    }
}

extern "C" void kernel_launch(void* const* d_in, const int* in_sizes, int n_in,
                              void* d_out, int out_size, void* d_ws, size_t ws_size,
                              hipStream_t stream) {
    const float* x  = (const float*)d_in[0];
    const float* Wq = (const float*)d_in[1];
    const float* Wk = (const float*)d_in[2];
    const float* Wv = (const float*)d_in[3];
    const float* Wp = (const float*)d_in[4];
    const float* bp = (const float*)d_in[5];
    float* out = (float*)d_out;

    // workspace layout (bf16 elements); total ~64.5 MB
    u16* xb  = (u16*)d_ws;            // 6291456  : x as bf16 [8192][768]
    u16* wb  = xb  + 6291456;         // 1769472  : Wq|Wk|Wv [2304][768]
    u16* wpb = wb  + 1769472;         // 589824   : Wp [768][768]
    u16* qo  = wpb + 589824;          // 6291456  : q [B,H,N,D] (scaled by 0.125)
    u16* ko  = qo  + 6291456;         // 6291456  : k [B,H,N,D]
    u16* vto = ko  + 6291456;         // 6291456  : v^T [B,H,D,N]
    u16* ao  = vto + 6291456;         // 6291456  : attn out [B,N,H*D]

    cast_all<<<8448, 256, 0, stream>>>(x, Wq, Wk, Wv, Wp, xb, wb, wpb);
    gemm_qkv<<<dim3(12, 64), 512, 0, stream>>>(xb, wb, qo, ko, vto);
    attn_fwd<<<dim3(96, 8), 256, 0, stream>>>(qo, ko, vto, ao);
    gemm_proj<<<dim3(8, 64), 256, 0, stream>>>(ao, wpb, bp, out);
}

// Round 8
// 187.587 us; speedup vs baseline: 1.4754x; 1.4754x over previous
//
#include <hip/hip_runtime.h>

typedef unsigned short u16;
typedef __attribute__((ext_vector_type(8))) __bf16 bf16x8;
typedef __attribute__((ext_vector_type(4))) float f32x4;
typedef __attribute__((ext_vector_type(16))) float f32x16;

__device__ __forceinline__ u16 f2bf(float f) {
    union { float f; unsigned u; } v; v.f = f;
    unsigned u = v.u;
    u += 0x7FFFu + ((u >> 16) & 1u);
    return (u16)(u >> 16);
}

// pack two f32 -> u32 of 2x bf16 (RNE); compiler emits v_cvt_pk_bf16_f32 (m240)
__device__ __forceinline__ unsigned pk2(float lo, float hi) {
    union { __bf16 h[2]; unsigned u; } x;
    x.h[0] = (__bf16)lo; x.h[1] = (__bf16)hi;
    return x.u;
}
// exchange upper 32 lanes of a with lower 32 lanes of b (compiler-managed hazards)
__device__ __forceinline__ void pswap(unsigned &a, unsigned &b) {
    auto r = __builtin_amdgcn_permlane32_swap(a, b, false, false);
    a = r[0]; b = r[1];
}

// async global->LDS copy, 16B per lane (m97 pattern)
typedef const __attribute__((address_space(1))) void GV;
typedef __attribute__((address_space(3))) void LV;
__device__ __forceinline__ void gl2lds16(const void* g, void* l) {
    __builtin_amdgcn_global_load_lds((GV*)g, (LV*)l, 16, 0, 0);
}

// ---------------- fused cast fp32 -> bf16 (x + 4 weights in ONE launch) ----------------
__global__ __launch_bounds__(256) void cast_all(
    const float* __restrict__ x,  const float* __restrict__ Wq,
    const float* __restrict__ Wk, const float* __restrict__ Wv,
    const float* __restrict__ Wp,
    u16* __restrict__ xb, u16* __restrict__ wb, u16* __restrict__ wpb)
{
    int bid = blockIdx.x;
    const float4* s; ushort4* d; int idx;
    if (bid < 6144) {                    // x: 1572864 float4 = 6144 blocks
        s = (const float4*)x; d = (ushort4*)xb; idx = bid * 256 + threadIdx.x;
    } else {                             // weights: 147456 float4 = 576 blocks each
        int t = bid - 6144;
        int w = t / 576;
        idx = (t - w * 576) * 256 + threadIdx.x;
        s = (const float4*)(w == 0 ? Wq : w == 1 ? Wk : w == 2 ? Wv : Wp);
        d = (ushort4*)(w == 3 ? wpb : wb + w * 589824);
    }
    float4 f = s[idx];
    ushort4 o;
    o.x = f2bf(f.x); o.y = f2bf(f.y); o.z = f2bf(f.z); o.w = f2bf(f.w);
    d[idx] = o;
}

// ---------------- GEMM v9 staging: BK=32 tiles, LDS line-XOR swizzle ----------------
// Tile rows are 32 bf16 = 64 B; LDS stores 2-row LINES of 128 B / 8 chunks.
// Lane-linear LDS dest (global_load_lds constraint): phys chunk `pos` of line
// holds LOGICAL chunk pos ^ (line&7). Frag column read -> 2-way bank alias =
// free (verified SQ_LDS_BANK_CONFLICT=0, rounds 1/6/7).
__device__ __forceinline__ void stage_c(const u16* src, int k0, u16* lds, int i) {
    int line = i >> 3, pos = i & 7;
    int p = pos ^ (line & 7);                 // logical chunk in this phys slot
    int r = line * 2 + (p >> 2), c = p & 3;
    gl2lds16(src + (size_t)r * 768 + k0 + c * 8, lds + i * 8);
}
__device__ __forceinline__ const bf16x8* fragK(const u16* lds, int row, int quad) {
    int line = row >> 1;
    int pos = (((row & 1) << 2) | quad) ^ (line & 7);
    return reinterpret_cast<const bf16x8*>(lds + line * 64 + pos * 8);
}

// ---------------- QKV projection GEMM (v9.1: balanced grid, SPILL FIX) ----------------
// 64x12 = 768 blocks / 256 CU = exactly 3 work-blocks per CU (r0-r6 had 2.25/CU
// -> 1.33x makespan imbalance). ROUND-7 LESSON: __launch_bounds__(512,6) capped
// VGPR at ~85 < the ~100 the kernel needs -> full accumulator spill to scratch
// (VGPR_Count=40, WRITE_SIZE 427MB, 144us). Now (512,4): 128-VGPR budget, no
// spill, 2 blocks resident (16 waves/CU) while the grid stays balanced at 3/CU.
__global__ __launch_bounds__(512, 4) void gemm_qkv(
    const u16* __restrict__ A, const u16* __restrict__ Bm,
    u16* __restrict__ qo, u16* __restrict__ ko, u16* __restrict__ vto)
{
    __shared__ u16 As[2][4096];          // 2 x  8 KB (128 rows x 32)
    __shared__ u16 Bs[2][6144];          // 2 x 12 KB (192 rows x 32)
    const int tid = threadIdx.x;
    const int wave = tid >> 6, lane = tid & 63;
    const int quad = lane >> 4, l16 = lane & 15;
    const int wm = wave >> 2, wn = wave & 3;      // 2M x 4N waves, per-wave 64x48
    // XCD-chunked swizzle (T1): 768 blocks = 8 XCDs x 96 (bijective, 768%8==0)
    const int id = blockIdx.x + 12 * blockIdx.y;
    const int nid = (id & 7) * 96 + (id >> 3);
    const int bx = nid % 12, by = nid / 12;
    const int rowBase = by * 128;
    const int colBase = bx * 192;

    const u16* aSrc = A + (size_t)rowBase * 768;
    const u16* bSrc = Bm + (size_t)colBase * 768;
    f32x4 acc[4][3] = {};

    // stage one BK=32 tile: A 512 chunks (1/thread), B 768 chunks (1.5/thread,
    // wave-uniform split at tid<256 = waves 0-3)
    auto stage = [&](int buf, int k0) {
        stage_c(aSrc, k0, As[buf], tid);
        stage_c(bSrc, k0, Bs[buf], tid);
        if (tid < 256) stage_c(bSrc, k0, Bs[buf], 512 + tid);
    };

    stage(0, 0);
    __syncthreads();                     // tile 0 staged (vmcnt drained at barrier)

    int buf = 0;
    for (int t = 0; t < 24; t++) {
        if (t + 1 < 24) stage(buf ^ 1, (t + 1) * 32);   // prefetch next tile
        bf16x8 a[4], b[3];
        #pragma unroll
        for (int mi = 0; mi < 4; mi++) a[mi] = *fragK(As[buf], wm * 64 + mi * 16 + l16, quad);
        #pragma unroll
        for (int ni = 0; ni < 3; ni++) b[ni] = *fragK(Bs[buf], wn * 48 + ni * 16 + l16, quad);
        __builtin_amdgcn_s_setprio(1);
        #pragma unroll
        for (int mi = 0; mi < 4; mi++)
            #pragma unroll
            for (int ni = 0; ni < 3; ni++)
                acc[mi][ni] = __builtin_amdgcn_mfma_f32_16x16x32_bf16(a[mi], b[ni], acc[mi][ni], 0, 0, 0);
        __builtin_amdgcn_s_setprio(0);
        __syncthreads();                 // reads of buf done; next tile's stage drained
        buf ^= 1;
    }

    #pragma unroll
    for (int mi = 0; mi < 4; mi++) {
        #pragma unroll
        for (int ni = 0; ni < 3; ni++) {
            int gj = colBase + wn * 48 + ni * 16 + l16;   // 0..2303
            int which = gj / 768;                         // 0=q,1=k,2=v (uniform per frag)
            int r = gj - which * 768;
            int h = r >> 6, d = r & 63;
            int gi0 = rowBase + wm * 64 + mi * 16 + quad * 4;
            int b_ = gi0 >> 10;                           // constant across 4 rows
            int n0 = gi0 & 1023;
            if (which == 2) {
                ushort4 pk;
                pk.x = f2bf(acc[mi][ni][0]);
                pk.y = f2bf(acc[mi][ni][1]);
                pk.z = f2bf(acc[mi][ni][2]);
                pk.w = f2bf(acc[mi][ni][3]);
                *reinterpret_cast<ushort4*>(vto + ((size_t)(b_ * 12 + h) * 64 + d) * 1024 + n0) = pk;
            } else {
                float s = (which == 0) ? 0.125f : 1.0f;
                u16* dst = (which == 0 ? qo : ko) + ((size_t)(b_ * 12 + h) * 1024 + n0) * 64 + d;
                #pragma unroll
                for (int rr = 0; rr < 4; rr++)
                    dst[(size_t)rr * 64] = f2bf(acc[mi][ni][rr] * s);
            }
        }
    }
}

// ---------------- fused flash attention (v9.1, unchanged) ----------------
__global__ __launch_bounds__(256, 3) void attn_fwd(
    const u16* __restrict__ q, const u16* __restrict__ k,
    const u16* __restrict__ vt, u16* __restrict__ ao)
{
    __shared__ u16 Ks[2][4096];      // [key 0..63][d-chunk phys 0..7][8 bf16]
    __shared__ u16 Vs[2][4096];      // [d 0..63][key-chunk phys 0..7][8 bf16]
    const int bh = blockIdx.x, qt = blockIdx.y;   // bh fast => same head -> same XCD
    const int b = bh / 12, h = bh - b * 12;
    const int tid = threadIdx.x;
    const int wave = tid >> 6, lane = tid & 63;
    const int l31 = lane & 31, hi = lane >> 5;
    const int sw = l31 & 7;

    const u16* qb = q + (size_t)bh * 65536 + ((size_t)qt * 128 + wave * 32) * 64;
    const u16* kb = k + (size_t)bh * 65536;
    const u16* vb = vt + (size_t)bh * 65536;

    auto stage = [&](int buf, int j0) {
        #pragma unroll
        for (int r = 0; r < 2; r++) {
            int i = r * 256 + tid;               // 0..511, 16B each
            int row = i >> 3, cp = i & 7;
            int cl = cp ^ (row & 7);
            gl2lds16((const char*)kb + (size_t)(j0 + row) * 128 + cl * 16,
                     (char*)&Ks[buf][0] + i * 16);
        }
        #pragma unroll
        for (int r = 0; r < 2; r++) {
            int i = r * 256 + tid;
            int row = i >> 3, cp = i & 7;
            int cl = cp ^ (row & 7);
            gl2lds16((const char*)vb + (size_t)row * 2048 + (size_t)j0 * 2 + cl * 16,
                     (char*)&Vs[buf][0] + i * 16);
        }
    };

    stage(0, 0);

    bf16x8 qf[4];
    #pragma unroll
    for (int dk = 0; dk < 4; dk++)
        qf[dk] = *reinterpret_cast<const bf16x8*>(qb + l31 * 64 + dk * 16 + hi * 8);

    f32x16 o0 = {}, o1 = {};         // O[query 32][d 0-31 / 32-63]
    float lsum = 0.f;                // partial row-sum for query l31

    __syncthreads();

    int buf = 0;
    for (int j0 = 0; j0 < 1024; j0 += 64) {
        if (j0 + 64 < 1024) stage(buf ^ 1, j0 + 64);

        f32x16 s0 = {}, s1 = {};
        #pragma unroll
        for (int dk = 0; dk < 4; dk++) {
            int ch = ((2 * dk + hi) ^ sw) * 8;
            bf16x8 kf0 = *reinterpret_cast<const bf16x8*>(&Ks[buf][l31 * 64 + ch]);
            bf16x8 kf1 = *reinterpret_cast<const bf16x8*>(&Ks[buf][(32 + l31) * 64 + ch]);
            s0 = __builtin_amdgcn_mfma_f32_32x32x16_bf16(kf0, qf[dk], s0, 0, 0, 0);
            s1 = __builtin_amdgcn_mfma_f32_32x32x16_bf16(kf1, qf[dk], s1, 0, 0, 0);
        }

        bf16x8 pa[4];
        #pragma unroll
        for (int kbk = 0; kbk < 2; kbk++) {
            float p[16];
            #pragma unroll
            for (int r = 0; r < 16; r++) {
                p[r] = __expf(kbk ? s1[r] : s0[r]);
                lsum += p[r];
            }
            unsigned W00 = pk2(p[0],  p[1]),  W01 = pk2(p[2],  p[3]);
            unsigned W10 = pk2(p[4],  p[5]),  W11 = pk2(p[6],  p[7]);
            unsigned W20 = pk2(p[8],  p[9]),  W21 = pk2(p[10], p[11]);
            unsigned W30 = pk2(p[12], p[13]), W31 = pk2(p[14], p[15]);
            pswap(W00, W10); pswap(W01, W11);
            pswap(W20, W30); pswap(W21, W31);
            union { unsigned u[4]; bf16x8 v; } pk0, pk1;
            pk0.u[0] = W00; pk0.u[1] = W01; pk0.u[2] = W10; pk0.u[3] = W11;
            pk1.u[0] = W20; pk1.u[1] = W21; pk1.u[2] = W30; pk1.u[3] = W31;
            pa[kbk * 2 + 0] = pk0.v;
            pa[kbk * 2 + 1] = pk1.v;
        }

        #pragma unroll
        for (int ks = 0; ks < 4; ks++) {
            int ch = ((2 * ks + hi) ^ sw) * 8;
            bf16x8 vf0 = *reinterpret_cast<const bf16x8*>(&Vs[buf][l31 * 64 + ch]);
            bf16x8 vf1 = *reinterpret_cast<const bf16x8*>(&Vs[buf][(32 + l31) * 64 + ch]);
            o0 = __builtin_amdgcn_mfma_f32_32x32x16_bf16(pa[ks], vf0, o0, 0, 0, 0);
            o1 = __builtin_amdgcn_mfma_f32_32x32x16_bf16(pa[ks], vf1, o1, 0, 0, 0);
        }

        __syncthreads();
        buf ^= 1;
    }

    lsum += __shfl_xor(lsum, 32, 64);

    #pragma unroll
    for (int r = 0; r < 16; r++) {
        int qrow = (r & 3) + 8 * (r >> 2) + 4 * hi;
        float lv = __shfl(lsum, qrow, 32);
        float inv = 1.0f / lv;
        int n = qt * 128 + wave * 32 + qrow;
        size_t base = (size_t)(b * 1024 + n) * 768 + h * 64;
        ao[base + l31]      = f2bf(o0[r] * inv);
        ao[base + 32 + l31] = f2bf(o1[r] * inv);
    }
}

// ---------------- output projection GEMM (v9: BM=128/BN=96, 512 blocks = 2.0/CU) ----------------
__global__ __launch_bounds__(256, 3) void gemm_proj(
    const u16* __restrict__ A, const u16* __restrict__ Bm,
    const float* __restrict__ bias, float* __restrict__ out)
{
    __shared__ u16 As[2][4096];          // 2 x 8 KB (128 x 32)
    __shared__ u16 Bs[2][3072];          // 2 x 6 KB ( 96 x 32)
    const int tid = threadIdx.x;
    const int wave = tid >> 6, lane = tid & 63;
    const int quad = lane >> 4, l16 = lane & 15;
    const int wm = wave >> 1, wn = wave & 1;      // 2M x 2N waves, per-wave 64x48
    // XCD-chunked swizzle: 512 blocks = 8 XCDs x 64 (bijective)
    const int id = blockIdx.x + 8 * blockIdx.y;
    const int nid = (id & 7) * 64 + (id >> 3);
    const int bx = nid % 8, by = nid / 8;
    const int rowBase = by * 128;
    const int colBase = bx * 96;

    const u16* aSrc = A + (size_t)rowBase * 768;
    const u16* bSrc = Bm + (size_t)colBase * 768;
    f32x4 acc[4][3] = {};

    // A 512 chunks (2/thread), B 384 chunks (1.5/thread, split at tid<128 = waves 0-1)
    auto stage = [&](int buf, int k0) {
        stage_c(aSrc, k0, As[buf], tid);
        stage_c(aSrc, k0, As[buf], 256 + tid);
        stage_c(bSrc, k0, Bs[buf], tid);
        if (tid < 128) stage_c(bSrc, k0, Bs[buf], 256 + tid);
    };

    stage(0, 0);
    __syncthreads();

    int buf = 0;
    for (int t = 0; t < 24; t++) {
        if (t + 1 < 24) stage(buf ^ 1, (t + 1) * 32);
        bf16x8 a[4], b[3];
        #pragma unroll
        for (int mi = 0; mi < 4; mi++) a[mi] = *fragK(As[buf], wm * 64 + mi * 16 + l16, quad);
        #pragma unroll
        for (int ni = 0; ni < 3; ni++) b[ni] = *fragK(Bs[buf], wn * 48 + ni * 16 + l16, quad);
        __builtin_amdgcn_s_setprio(1);
        #pragma unroll
        for (int mi = 0; mi < 4; mi++)
            #pragma unroll
            for (int ni = 0; ni < 3; ni++)
                acc[mi][ni] = __builtin_amdgcn_mfma_f32_16x16x32_bf16(a[mi], b[ni], acc[mi][ni], 0, 0, 0);
        __builtin_amdgcn_s_setprio(0);
        __syncthreads();
        buf ^= 1;
    }

    #pragma unroll
    for (int mi = 0; mi < 4; mi++) {
        #pragma unroll
        for (int ni = 0; ni < 3; ni++) {
            int gj = colBase + wn * 48 + ni * 16 + l16;
            float bv = bias[gj];
            int gi0 = rowBase + wm * 64 + mi * 16 + quad * 4;
            #pragma unroll
            for (int rr2 = 0; rr2 < 4; rr2++)
                out[(size_t)(gi0 + rr2) * 768 + gj] = acc[mi][ni][rr2] + bv;
        }
    }
}

extern "C" void kernel_launch(void* const* d_in, const int* in_sizes, int n_in,
                              void* d_out, int out_size, void* d_ws, size_t ws_size,
                              hipStream_t stream) {
    const float* x  = (const float*)d_in[0];
    const float* Wq = (const float*)d_in[1];
    const float* Wk = (const float*)d_in[2];
    const float* Wv = (const float*)d_in[3];
    const float* Wp = (const float*)d_in[4];
    const float* bp = (const float*)d_in[5];
    float* out = (float*)d_out;

    // workspace layout (bf16 elements); total ~64.5 MB
    u16* xb  = (u16*)d_ws;            // 6291456  : x as bf16 [8192][768]
    u16* wb  = xb  + 6291456;         // 1769472  : Wq|Wk|Wv [2304][768]
    u16* wpb = wb  + 1769472;         // 589824   : Wp [768][768]
    u16* qo  = wpb + 589824;          // 6291456  : q [B,H,N,D] (scaled by 0.125)
    u16* ko  = qo  + 6291456;         // 6291456  : k [B,H,N,D]
    u16* vto = ko  + 6291456;         // 6291456  : v^T [B,H,D,N]
    u16* ao  = vto + 6291456;         // 6291456  : attn out [B,N,H*D]

    cast_all<<<8448, 256, 0, stream>>>(x, Wq, Wk, Wv, Wp, xb, wb, wpb);
    gemm_qkv<<<dim3(12, 64), 512, 0, stream>>>(xb, wb, qo, ko, vto);
    attn_fwd<<<dim3(96, 8), 256, 0, stream>>>(qo, ko, vto, ao);
    gemm_proj<<<dim3(8, 64), 256, 0, stream>>>(ao, wpb, bp, out);
}